// Round 1
// baseline (993.666 us; speedup 1.0000x reference)
//
#include <hip/hip_runtime.h>

typedef __attribute__((ext_vector_type(8))) short bf16x8;
typedef __attribute__((ext_vector_type(4))) float f32x4;

#define HID 768
#define NH 12
#define HD 64

__device__ inline float b2f(unsigned short x) {
  return __builtin_bit_cast(float, ((unsigned)x) << 16);
}
__device__ inline unsigned short f2b(float f) {
  unsigned u = __builtin_bit_cast(unsigned, f);
  u += 0x7fffu + ((u >> 16) & 1u);  // RNE
  return (unsigned short)(u >> 16);
}

// ---------------- cast fp32 -> bf16 (vectorized) ----------------
__global__ __launch_bounds__(256) void cast_bf16(const float* __restrict__ in,
                                                 unsigned short* __restrict__ out, int n4) {
  int t = blockIdx.x * 256 + threadIdx.x;
  if (t >= n4) return;
  float4 v = ((const float4*)in)[t];
  ushort4 o;
  o.x = f2b(v.x); o.y = f2b(v.y); o.z = f2b(v.z); o.w = f2b(v.w);
  ((ushort4*)out)[t] = o;
}

// ---------------- weight prep: permute rows to head-major, cast bf16 ----------------
// mats 0..2 (Wq,Wk,Wv): out[h*64+d][k] = W[d*12+h][k]  (mat 0 scaled by 0.125)
// mat 3 (Wo):           out[j][h*64+d] = Wo[j][d*12+h]
__global__ __launch_bounds__(256) void prep_weights(
    const float* __restrict__ Wq, const float* __restrict__ Wk,
    const float* __restrict__ Wv, const float* __restrict__ Wo,
    unsigned short* __restrict__ wq, unsigned short* __restrict__ wk,
    unsigned short* __restrict__ wv, unsigned short* __restrict__ wo) {
  int mat = blockIdx.y;
  int o = blockIdx.x * 256 + threadIdx.x;  // < 768*768
  int jrow = o / HID, c = o - jrow * HID;
  float val;
  unsigned short* dst;
  if (mat < 3) {
    int h = jrow >> 6, d = jrow & 63;
    const float* W = (mat == 0) ? Wq : ((mat == 1) ? Wk : Wv);
    val = W[(d * NH + h) * HID + c];
    if (mat == 0) val *= 0.125f;  // fold q scale = HEAD_DIM^-0.5
    dst = (mat == 0) ? wq : ((mat == 1) ? wk : wv);
  } else {
    int h = c >> 6, d = c & 63;
    val = Wo[(size_t)jrow * HID + d * NH + h];
    dst = wo;
  }
  dst[o] = f2b(val);
}

__global__ void prep_bias(const float* __restrict__ bq, const float* __restrict__ bk,
                          const float* __restrict__ bv, float* __restrict__ bqp,
                          float* __restrict__ bkp, float* __restrict__ bvp) {
  int j = threadIdx.x;
  if (j >= HID) return;
  int h = j >> 6, d = j & 63, s = d * NH + h;
  bqp[j] = bq[s] * 0.125f;
  bkp[j] = bk[s];
  bvp[j] = bv[s];
}

// ---------------- bf16 MFMA GEMM: C[M][Nn] = A[M][K] * B[Nn][K]^T + bias ----------------
// 128x128 tile, BK=32, 4 waves (2x2 of 64x64), 16x16x32 MFMA.
// global_load_lds(16B) with pre-swizzled SOURCE + XOR-swizzled ds_read (rule #21).
template <int OUT_F32>
__global__ __launch_bounds__(256) void gemm_nt(
    const unsigned short* __restrict__ A, const unsigned short* __restrict__ B,
    const float* __restrict__ bias, void* __restrict__ Cv, int M, int Nn, int K) {
  __shared__ __align__(16) unsigned short As[128 * 32];
  __shared__ __align__(16) unsigned short Bs[128 * 32];
  const int tid = threadIdx.x;
  const int lane = tid & 63;
  const int wid = tid >> 6;
  const int wr = wid >> 1, wc = wid & 1;
  const int l16 = lane & 15, kq = lane >> 4;
  const int m0 = blockIdx.x * 128;
  const int n0 = blockIdx.y * 128;

  f32x4 acc[4][4];
#pragma unroll
  for (int i = 0; i < 4; ++i)
#pragma unroll
    for (int j = 0; j < 4; ++j) acc[i][j] = (f32x4){0.f, 0.f, 0.f, 0.f};

  const int srow = tid >> 2;            // 0..63
  const int skg = tid & 3;              // 16B-group within 64B row
  const int scol = (skg ^ ((srow >> 1) & 3)) * 8;  // pre-swizzled source column (same for row and row+64)
  const int sbase = (tid & ~63) * 8;    // wave-uniform LDS element base

  const unsigned short* Ag = A + (size_t)(m0 + srow) * K + scol;
  const unsigned short* Bg = B + (size_t)(n0 + srow) * K + scol;
  const int kqA0 = (kq ^ ((l16 >> 1) & 3)) * 8;  // swizzled k-group for reads (rows base%16==0)

  for (int k0 = 0; k0 < K; k0 += 32) {
    __builtin_amdgcn_global_load_lds((const __attribute__((address_space(1))) void*)(Ag + k0),
                                     (__attribute__((address_space(3))) void*)(As + sbase), 16, 0, 0);
    __builtin_amdgcn_global_load_lds((const __attribute__((address_space(1))) void*)(Ag + (size_t)64 * K + k0),
                                     (__attribute__((address_space(3))) void*)(As + 2048 + sbase), 16, 0, 0);
    __builtin_amdgcn_global_load_lds((const __attribute__((address_space(1))) void*)(Bg + k0),
                                     (__attribute__((address_space(3))) void*)(Bs + sbase), 16, 0, 0);
    __builtin_amdgcn_global_load_lds((const __attribute__((address_space(1))) void*)(Bg + (size_t)64 * K + k0),
                                     (__attribute__((address_space(3))) void*)(Bs + 2048 + sbase), 16, 0, 0);
    __syncthreads();  // drains vmcnt before reads

    bf16x8 af[4], bf[4];
#pragma unroll
    for (int i = 0; i < 4; ++i) {
      int ra = wr * 64 + i * 16 + l16;
      af[i] = *(const bf16x8*)(As + ra * 32 + kqA0);
      int rb = wc * 64 + i * 16 + l16;
      bf[i] = *(const bf16x8*)(Bs + rb * 32 + kqA0);
    }
#pragma unroll
    for (int mi = 0; mi < 4; ++mi)
#pragma unroll
      for (int ni = 0; ni < 4; ++ni)
        acc[mi][ni] = __builtin_amdgcn_mfma_f32_16x16x32_bf16(af[mi], bf[ni], acc[mi][ni], 0, 0, 0);
    __syncthreads();
  }

  float* Cf = (float*)Cv;
  unsigned short* Cb = (unsigned short*)Cv;
#pragma unroll
  for (int mi = 0; mi < 4; ++mi) {
    int grow = m0 + wr * 64 + mi * 16 + kq * 4;
#pragma unroll
    for (int ni = 0; ni < 4; ++ni) {
      int gcol = n0 + wc * 64 + ni * 16 + l16;
      float bv_ = bias[gcol];
#pragma unroll
      for (int r = 0; r < 4; ++r) {
        float v = acc[mi][ni][r] + bv_;
        if (OUT_F32)
          Cf[(size_t)(grow + r) * Nn + gcol] = v;
        else
          Cb[(size_t)(grow + r) * Nn + gcol] = f2b(v);
      }
    }
  }
}

// ---------------- rowptr from sorted row_idx (lower_bound per row) ----------------
__global__ __launch_bounds__(256) void build_rowptr(const int* __restrict__ row_idx,
                                                    int* __restrict__ rowptr, int n, int E_) {
  int t = blockIdx.x * 256 + threadIdx.x;
  if (t > n) return;
  int lo = 0, hi = E_;
  while (lo < hi) {
    int mid = (lo + hi) >> 1;
    if (row_idx[mid] < t) lo = mid + 1; else hi = mid;
  }
  rowptr[t] = lo;
}

// ---------------- SDDMM: scores[e][h] = dot64(q[row[e]][h][:], k[col[e]][h][:]) ----------------
__global__ __launch_bounds__(256) void sddmm(const unsigned short* __restrict__ q,
                                             const unsigned short* __restrict__ k,
                                             const int* __restrict__ row_idx,
                                             const int* __restrict__ col_idx,
                                             float* __restrict__ scores, int E_) {
  int t = blockIdx.x * 256 + threadIdx.x;
  int e = t / NH;
  if (e >= E_) return;
  int h = t - e * NH;
  const bf16x8* qp = (const bf16x8*)(q + (size_t)row_idx[e] * HID + h * HD);
  const bf16x8* kp = (const bf16x8*)(k + (size_t)col_idx[e] * HID + h * HD);
  float s = 0.f;
#pragma unroll
  for (int i = 0; i < 8; ++i) {
    bf16x8 qa = qp[i], ka = kp[i];
#pragma unroll
    for (int j = 0; j < 8; ++j)
      s += b2f((unsigned short)qa[j]) * b2f((unsigned short)ka[j]);
  }
  scores[t] = s;
}

// ---------------- segment softmax in place, thread per (row, head) ----------------
__global__ __launch_bounds__(256) void seg_softmax(const int* __restrict__ rowptr,
                                                   float* __restrict__ scores, int n) {
  int t = blockIdx.x * 256 + threadIdx.x;
  int row = t / NH;
  if (row >= n) return;
  int h = t - row * NH;
  int s0 = rowptr[row], s1 = rowptr[row + 1];
  if (s0 >= s1) return;
  float m = -1e30f;
  for (int e = s0; e < s1; ++e) m = fmaxf(m, scores[(size_t)e * NH + h]);
  float sum = 0.f;
  for (int e = s0; e < s1; ++e) {
    float p = __expf(scores[(size_t)e * NH + h] - m);
    scores[(size_t)e * NH + h] = p;
    sum += p;
  }
  float inv = 1.f / sum;
  for (int e = s0; e < s1; ++e) scores[(size_t)e * NH + h] *= inv;
}

// ---------------- bspmm: out[t][h*64+d] = sum_e attn[e][h] * v[col[e]][h*64+d] ----------------
__global__ __launch_bounds__(256) void bspmm(const int* __restrict__ rowptr,
                                             const int* __restrict__ col_idx,
                                             const float* __restrict__ attn,
                                             const unsigned short* __restrict__ v,
                                             unsigned short* __restrict__ out) {
  int row = blockIdx.x;
  int j = threadIdx.x;  // col j, j+256, j+512
  int s0 = rowptr[row], s1 = rowptr[row + 1];
  int h0 = j >> 6, h1 = (j + 256) >> 6, h2 = (j + 512) >> 6;
  float a0 = 0.f, a1 = 0.f, a2 = 0.f;
  for (int e = s0; e < s1; ++e) {
    int c = col_idx[e];
    const unsigned short* vr = v + (size_t)c * HID;
    const float* ar = attn + (size_t)e * NH;
    a0 += ar[h0] * b2f(vr[j]);
    a1 += ar[h1] * b2f(vr[j + 256]);
    a2 += ar[h2] * b2f(vr[j + 512]);
  }
  size_t o = (size_t)row * HID + j;
  out[o] = f2b(a0);
  out[o + 256] = f2b(a1);
  out[o + 512] = f2b(a2);
}

// ---------------- launch ----------------
extern "C" void kernel_launch(void* const* d_in, const int* in_sizes, int n_in,
                              void* d_out, int out_size, void* d_ws, size_t ws_size,
                              hipStream_t stream) {
  const float* h_source = (const float*)d_in[0];
  const float* h_target = (const float*)d_in[1];
  const int* row_idx = (const int*)d_in[2];
  const int* col_idx = (const int*)d_in[3];
  const float* Wq = (const float*)d_in[4];
  const float* bq = (const float*)d_in[5];
  const float* Wk = (const float*)d_in[6];
  const float* bk = (const float*)d_in[7];
  const float* Wv = (const float*)d_in[8];
  const float* bv = (const float*)d_in[9];
  const float* Wo = (const float*)d_in[10];
  const float* bo = (const float*)d_in[11];
  float* out = (float*)d_out;

  const int n = in_sizes[0] / HID;   // 32768
  const int E_ = in_sizes[2];        // 1048576

  char* ws = (char*)d_ws;
  size_t off = 0;
  auto alloc = [&](size_t bytes) -> void* {
    off = (off + 255) & ~(size_t)255;
    void* p = ws + off;
    off += bytes;
    return p;
  };
  unsigned short* htb = (unsigned short*)alloc((size_t)n * HID * 2);  // h_target bf16; reused as attn_out
  unsigned short* hsb = (unsigned short*)alloc((size_t)n * HID * 2);
  unsigned short* qb = (unsigned short*)alloc((size_t)n * HID * 2);
  unsigned short* kb = (unsigned short*)alloc((size_t)n * HID * 2);
  unsigned short* vb = (unsigned short*)alloc((size_t)n * HID * 2);
  float* scores = (float*)alloc((size_t)E_ * NH * 4);
  unsigned short* wqp = (unsigned short*)alloc(HID * HID * 2);
  unsigned short* wkp = (unsigned short*)alloc(HID * HID * 2);
  unsigned short* wvp = (unsigned short*)alloc(HID * HID * 2);
  unsigned short* wop = (unsigned short*)alloc(HID * HID * 2);
  float* bqp = (float*)alloc(HID * 4);
  float* bkp = (float*)alloc(HID * 4);
  float* bvp = (float*)alloc(HID * 4);
  int* rowptr = (int*)alloc((size_t)(n + 1) * 4);

  int n4 = n * HID / 4;
  cast_bf16<<<(n4 + 255) / 256, 256, 0, stream>>>(h_target, htb, n4);
  cast_bf16<<<(n4 + 255) / 256, 256, 0, stream>>>(h_source, hsb, n4);
  prep_weights<<<dim3(HID * HID / 256, 4), 256, 0, stream>>>(Wq, Wk, Wv, Wo, wqp, wkp, wvp, wop);
  prep_bias<<<1, HID, 0, stream>>>(bq, bk, bv, bqp, bkp, bvp);

  dim3 gg(n / 128, HID / 128);
  gemm_nt<0><<<gg, 256, 0, stream>>>(htb, wqp, bqp, qb, n, HID, HID);
  gemm_nt<0><<<gg, 256, 0, stream>>>(hsb, wkp, bkp, kb, n, HID, HID);
  gemm_nt<0><<<gg, 256, 0, stream>>>(hsb, wvp, bvp, vb, n, HID, HID);

  build_rowptr<<<(n + 1 + 255) / 256, 256, 0, stream>>>(row_idx, rowptr, n, E_);
  sddmm<<<(E_ * NH + 255) / 256, 256, 0, stream>>>(qb, kb, row_idx, col_idx, scores, E_);
  seg_softmax<<<(n * NH + 255) / 256, 256, 0, stream>>>(rowptr, scores, n);
  bspmm<<<n, 256, 0, stream>>>(rowptr, col_idx, scores, vb, htb /* attn_out */);

  gemm_nt<1><<<gg, 256, 0, stream>>>(htb, wop, bo, out, n, HID, HID);
}

// Round 2
// 772.725 us; speedup vs baseline: 1.2859x; 1.2859x over previous
//
#include <hip/hip_runtime.h>

typedef __attribute__((ext_vector_type(8))) short bf16x8;
typedef __attribute__((ext_vector_type(4))) float f32x4;

#define HID 768
#define NH 12
#define HD 64

__device__ inline float b2f(unsigned short x) {
  return __builtin_bit_cast(float, ((unsigned)x) << 16);
}
__device__ inline unsigned short f2b(float f) {
  unsigned u = __builtin_bit_cast(unsigned, f);
  u += 0x7fffu + ((u >> 16) & 1u);  // RNE
  return (unsigned short)(u >> 16);
}

// ---------------- cast fp32 -> bf16 (vectorized) ----------------
__global__ __launch_bounds__(256) void cast_bf16(const float* __restrict__ in,
                                                 unsigned short* __restrict__ out, int n4) {
  int t = blockIdx.x * 256 + threadIdx.x;
  if (t >= n4) return;
  float4 v = ((const float4*)in)[t];
  ushort4 o;
  o.x = f2b(v.x); o.y = f2b(v.y); o.z = f2b(v.z); o.w = f2b(v.w);
  ((ushort4*)out)[t] = o;
}

// ---------------- weight prep: permute rows to head-major, cast bf16 ----------------
__global__ __launch_bounds__(256) void prep_weights(
    const float* __restrict__ Wq, const float* __restrict__ Wk,
    const float* __restrict__ Wv, const float* __restrict__ Wo,
    unsigned short* __restrict__ wq, unsigned short* __restrict__ wk,
    unsigned short* __restrict__ wv, unsigned short* __restrict__ wo) {
  int mat = blockIdx.y;
  int o = blockIdx.x * 256 + threadIdx.x;  // < 768*768
  int jrow = o / HID, c = o - jrow * HID;
  float val;
  unsigned short* dst;
  if (mat < 3) {
    int h = jrow >> 6, d = jrow & 63;
    const float* W = (mat == 0) ? Wq : ((mat == 1) ? Wk : Wv);
    val = W[(d * NH + h) * HID + c];
    if (mat == 0) val *= 0.125f;  // fold q scale
    dst = (mat == 0) ? wq : ((mat == 1) ? wk : wv);
  } else {
    int h = c >> 6, d = c & 63;
    val = Wo[(size_t)jrow * HID + d * NH + h];
    dst = wo;
  }
  dst[o] = f2b(val);
}

__global__ void prep_bias(const float* __restrict__ bq, const float* __restrict__ bk,
                          const float* __restrict__ bv, float* __restrict__ bqp,
                          float* __restrict__ bkp, float* __restrict__ bvp) {
  int j = threadIdx.x;
  if (j >= HID) return;
  int h = j >> 6, d = j & 63, s = d * NH + h;
  bqp[j] = bq[s] * 0.125f;
  bkp[j] = bk[s];
  bvp[j] = bv[s];
}

// ---------------- bf16 MFMA GEMM, 128x128 tile, BK=32, double-buffered prefetch ----------------
template <int OUT_F32>
__global__ __launch_bounds__(256) void gemm_nt(
    const unsigned short* __restrict__ A, const unsigned short* __restrict__ B,
    const float* __restrict__ bias, void* __restrict__ Cv, int M, int Nn, int K) {
  __shared__ __align__(16) unsigned short As[2][128 * 32];
  __shared__ __align__(16) unsigned short Bs[2][128 * 32];
  const int tid = threadIdx.x;
  const int lane = tid & 63;
  const int wid = tid >> 6;
  const int wr = wid >> 1, wc = wid & 1;
  const int l16 = lane & 15, kq = lane >> 4;
  const int m0 = blockIdx.x * 128;
  const int n0 = blockIdx.y * 128;

  f32x4 acc[4][4];
#pragma unroll
  for (int i = 0; i < 4; ++i)
#pragma unroll
    for (int j = 0; j < 4; ++j) acc[i][j] = (f32x4){0.f, 0.f, 0.f, 0.f};

  const int srow = tid >> 2;
  const int skg = tid & 3;
  const int scol = (skg ^ ((srow >> 1) & 3)) * 8;  // pre-swizzled source col
  const int sbase = (tid & ~63) * 8;               // wave-uniform LDS elem base

  const unsigned short* Ag = A + (size_t)(m0 + srow) * K + scol;
  const unsigned short* Bg = B + (size_t)(n0 + srow) * K + scol;
  const int kqA0 = (kq ^ ((l16 >> 1) & 3)) * 8;    // swizzled k-group for reads

#define STAGE(buf, kk)                                                                              \
  do {                                                                                              \
    __builtin_amdgcn_global_load_lds((const __attribute__((address_space(1))) void*)(Ag + (kk)),    \
                                     (__attribute__((address_space(3))) void*)(&As[buf][0] + sbase), 16, 0, 0); \
    __builtin_amdgcn_global_load_lds((const __attribute__((address_space(1))) void*)(Ag + (size_t)64 * K + (kk)), \
                                     (__attribute__((address_space(3))) void*)(&As[buf][0] + 2048 + sbase), 16, 0, 0); \
    __builtin_amdgcn_global_load_lds((const __attribute__((address_space(1))) void*)(Bg + (kk)),    \
                                     (__attribute__((address_space(3))) void*)(&Bs[buf][0] + sbase), 16, 0, 0); \
    __builtin_amdgcn_global_load_lds((const __attribute__((address_space(1))) void*)(Bg + (size_t)64 * K + (kk)), \
                                     (__attribute__((address_space(3))) void*)(&Bs[buf][0] + 2048 + sbase), 16, 0, 0); \
  } while (0)

  STAGE(0, 0);
  __syncthreads();  // drain stage 0
  int cur = 0;
  for (int k0 = 0; k0 < K; k0 += 32) {
    if (k0 + 32 < K) STAGE(cur ^ 1, k0 + 32);  // prefetch overlaps compute below
    bf16x8 af[4], bfr[4];
#pragma unroll
    for (int i = 0; i < 4; ++i) {
      int ra = wr * 64 + i * 16 + l16;
      af[i] = *(const bf16x8*)(&As[cur][0] + ra * 32 + kqA0);
      int rb = wc * 64 + i * 16 + l16;
      bfr[i] = *(const bf16x8*)(&Bs[cur][0] + rb * 32 + kqA0);
    }
#pragma unroll
    for (int mi = 0; mi < 4; ++mi)
#pragma unroll
      for (int ni = 0; ni < 4; ++ni)
        acc[mi][ni] = __builtin_amdgcn_mfma_f32_16x16x32_bf16(af[mi], bfr[ni], acc[mi][ni], 0, 0, 0);
    __syncthreads();  // drains prefetch vmcnt + protects buffer reuse
    cur ^= 1;
  }
#undef STAGE

  float* Cf = (float*)Cv;
  unsigned short* Cb = (unsigned short*)Cv;
#pragma unroll
  for (int mi = 0; mi < 4; ++mi) {
    int grow = m0 + wr * 64 + mi * 16 + kq * 4;
#pragma unroll
    for (int ni = 0; ni < 4; ++ni) {
      int gcol = n0 + wc * 64 + ni * 16 + l16;
      float bv_ = bias[gcol];
#pragma unroll
      for (int r = 0; r < 4; ++r) {
        float v = acc[mi][ni][r] + bv_;
        if (OUT_F32)
          Cf[(size_t)(grow + r) * Nn + gcol] = v;
        else
          Cb[(size_t)(grow + r) * Nn + gcol] = f2b(v);
      }
    }
  }
}

// ---------------- rowptr from sorted row_idx ----------------
__global__ __launch_bounds__(256) void build_rowptr(const int* __restrict__ row_idx,
                                                    int* __restrict__ rowptr, int n, int E_) {
  int t = blockIdx.x * 256 + threadIdx.x;
  if (t > n) return;
  int lo = 0, hi = E_;
  while (lo < hi) {
    int mid = (lo + hi) >> 1;
    if (row_idx[mid] < t) lo = mid + 1; else hi = mid;
  }
  rowptr[t] = lo;
}

// ---------------- SDDMM v2: half-wave (32 lanes) per edge, coalesced ----------------
// lane ql handles 16B chunks j*32+ql (j=0..2); head of chunk c is c>>3.
// per-head dot reduced via shfl_xor butterfly within 8-lane groups.
__global__ __launch_bounds__(256) void sddmm2(const unsigned short* __restrict__ q,
                                              const unsigned short* __restrict__ k,
                                              const int* __restrict__ row_idx,
                                              const int* __restrict__ col_idx,
                                              float* __restrict__ scores, int E_) {
  int t = blockIdx.x * 256 + threadIdx.x;
  int e = t >> 5;
  if (e >= E_) return;
  int ql = threadIdx.x & 31;
  const bf16x8* qp = (const bf16x8*)(q + (size_t)row_idx[e] * HID);
  const bf16x8* kp = (const bf16x8*)(k + (size_t)col_idx[e] * HID);
  float p[3];
#pragma unroll
  for (int j = 0; j < 3; ++j) {
    int c = j * 32 + ql;
    bf16x8 qa = qp[c], ka = kp[c];
    float s = 0.f;
#pragma unroll
    for (int i = 0; i < 8; ++i)
      s += b2f((unsigned short)qa[i]) * b2f((unsigned short)ka[i]);
    p[j] = s;
  }
#pragma unroll
  for (int j = 0; j < 3; ++j) {
    float s = p[j];
    s += __shfl_xor(s, 1);
    s += __shfl_xor(s, 2);
    s += __shfl_xor(s, 4);
    if ((ql & 7) == 0) scores[(size_t)e * NH + j * 4 + (ql >> 3)] = s;
  }
}

// ---------------- fused segment-softmax + SpMM: one wave per target row ----------------
// phase 1: per-head max & exp-sum over the row's contiguous score segment (48 lanes).
// phase 2: gather v rows (ushort4/lane, coalesced), weight by softmax, accumulate f32.
__global__ __launch_bounds__(256) void spmm_sm(const int* __restrict__ rowptr,
                                               const int* __restrict__ col_idx,
                                               const float* __restrict__ scores,
                                               const unsigned short* __restrict__ v,
                                               unsigned short* __restrict__ out, int n) {
  int lane = threadIdx.x & 63;
  int row = blockIdx.x * 4 + (threadIdx.x >> 6);
  if (row >= n) return;
  int s0 = rowptr[row], s1 = rowptr[row + 1];
  size_t obase = (size_t)row * HID;
  if (s0 >= s1) {
    ushort4 z = {0, 0, 0, 0};
#pragma unroll
    for (int pp = 0; pp < 3; ++pp) ((ushort4*)(out + obase))[pp * 64 + lane] = z;
    return;
  }
  // phase 1: lane = h*4 + i over 48 lanes
  int h12 = lane >> 2, i4 = lane & 3;
  float m = -1e30f;
  if (h12 < NH)
    for (int e = s0 + i4; e < s1; e += 4) m = fmaxf(m, scores[(size_t)e * NH + h12]);
  m = fmaxf(m, __shfl_xor(m, 1));
  m = fmaxf(m, __shfl_xor(m, 2));
  float sm = 0.f;
  if (h12 < NH)
    for (int e = s0 + i4; e < s1; e += 4) sm += __expf(scores[(size_t)e * NH + h12] - m);
  sm += __shfl_xor(sm, 1);
  sm += __shfl_xor(sm, 2);
  // broadcast per-chunk head params: chunk p covers head p*4 + (lane>>4)
  int hg = lane >> 4;
  float mh[3], ih[3];
#pragma unroll
  for (int pp = 0; pp < 3; ++pp) {
    int src = (pp * 4 + hg) << 2;
    mh[pp] = __shfl(m, src);
    ih[pp] = 1.f / __shfl(sm, src);
  }
  float4 acc[3] = {};
  for (int e = s0; e < s1; ++e) {
    int c = col_idx[e];
    const ushort4* vr = (const ushort4*)(v + (size_t)c * HID);
#pragma unroll
    for (int pp = 0; pp < 3; ++pp) {
      float a = __expf(scores[(size_t)e * NH + pp * 4 + hg] - mh[pp]) * ih[pp];
      ushort4 vv = vr[pp * 64 + lane];
      acc[pp].x += a * b2f(vv.x);
      acc[pp].y += a * b2f(vv.y);
      acc[pp].z += a * b2f(vv.z);
      acc[pp].w += a * b2f(vv.w);
    }
  }
#pragma unroll
  for (int pp = 0; pp < 3; ++pp) {
    ushort4 o;
    o.x = f2b(acc[pp].x); o.y = f2b(acc[pp].y);
    o.z = f2b(acc[pp].z); o.w = f2b(acc[pp].w);
    ((ushort4*)(out + obase))[pp * 64 + lane] = o;
  }
}

// ---------------- launch ----------------
extern "C" void kernel_launch(void* const* d_in, const int* in_sizes, int n_in,
                              void* d_out, int out_size, void* d_ws, size_t ws_size,
                              hipStream_t stream) {
  const float* h_source = (const float*)d_in[0];
  const float* h_target = (const float*)d_in[1];
  const int* row_idx = (const int*)d_in[2];
  const int* col_idx = (const int*)d_in[3];
  const float* Wq = (const float*)d_in[4];
  const float* bq = (const float*)d_in[5];
  const float* Wk = (const float*)d_in[6];
  const float* bk = (const float*)d_in[7];
  const float* Wv = (const float*)d_in[8];
  const float* bv = (const float*)d_in[9];
  const float* Wo = (const float*)d_in[10];
  const float* bo = (const float*)d_in[11];
  float* out = (float*)d_out;

  const int n = in_sizes[0] / HID;   // 32768
  const int E_ = in_sizes[2];        // 1048576

  char* ws = (char*)d_ws;
  size_t off = 0;
  auto alloc = [&](size_t bytes) -> void* {
    off = (off + 255) & ~(size_t)255;
    void* p = ws + off;
    off += bytes;
    return p;
  };
  unsigned short* htb = (unsigned short*)alloc((size_t)n * HID * 2);  // h_target bf16; reused as attn_out
  unsigned short* hsb = (unsigned short*)alloc((size_t)n * HID * 2);
  unsigned short* qb = (unsigned short*)alloc((size_t)n * HID * 2);
  unsigned short* kb = (unsigned short*)alloc((size_t)n * HID * 2);
  unsigned short* vb = (unsigned short*)alloc((size_t)n * HID * 2);
  float* scores = (float*)alloc((size_t)E_ * NH * 4);
  unsigned short* wqp = (unsigned short*)alloc(HID * HID * 2);
  unsigned short* wkp = (unsigned short*)alloc(HID * HID * 2);
  unsigned short* wvp = (unsigned short*)alloc(HID * HID * 2);
  unsigned short* wop = (unsigned short*)alloc(HID * HID * 2);
  float* bqp = (float*)alloc(HID * 4);
  float* bkp = (float*)alloc(HID * 4);
  float* bvp = (float*)alloc(HID * 4);
  int* rowptr = (int*)alloc((size_t)(n + 1) * 4);

  int n4 = n * HID / 4;
  cast_bf16<<<(n4 + 255) / 256, 256, 0, stream>>>(h_target, htb, n4);
  cast_bf16<<<(n4 + 255) / 256, 256, 0, stream>>>(h_source, hsb, n4);
  prep_weights<<<dim3(HID * HID / 256, 4), 256, 0, stream>>>(Wq, Wk, Wv, Wo, wqp, wkp, wvp, wop);
  prep_bias<<<1, HID, 0, stream>>>(bq, bk, bv, bqp, bkp, bvp);

  dim3 gg(n / 128, HID / 128);
  gemm_nt<0><<<gg, 256, 0, stream>>>(htb, wqp, bqp, qb, n, HID, HID);
  gemm_nt<0><<<gg, 256, 0, stream>>>(hsb, wkp, bkp, kb, n, HID, HID);
  gemm_nt<0><<<gg, 256, 0, stream>>>(hsb, wvp, bvp, vb, n, HID, HID);

  build_rowptr<<<(n + 1 + 255) / 256, 256, 0, stream>>>(row_idx, rowptr, n, E_);
  sddmm2<<<(int)(((size_t)E_ * 32 + 255) / 256), 256, 0, stream>>>(qb, kb, row_idx, col_idx, scores, E_);
  spmm_sm<<<(n + 3) / 4, 256, 0, stream>>>(rowptr, col_idx, scores, vb, htb /* attn_out */, n);

  gemm_nt<1><<<gg, 256, 0, stream>>>(htb, wop, bo, out, n, HID, HID);
}

// Round 3
// 741.319 us; speedup vs baseline: 1.3404x; 1.0424x over previous
//
#include <hip/hip_runtime.h>

typedef __attribute__((ext_vector_type(8))) short bf16x8;
typedef __attribute__((ext_vector_type(4))) float f32x4;

#define HID 768
#define NH 12
#define HD 64

__device__ inline float b2f(unsigned short x) {
  return __builtin_bit_cast(float, ((unsigned)x) << 16);
}
__device__ inline unsigned short f2b(float f) {
  unsigned u = __builtin_bit_cast(unsigned, f);
  u += 0x7fffu + ((u >> 16) & 1u);  // RNE
  return (unsigned short)(u >> 16);
}

// ---------------- cast fp32 -> bf16 (vectorized) ----------------
__global__ __launch_bounds__(256) void cast_bf16(const float* __restrict__ in,
                                                 unsigned short* __restrict__ out, int n4) {
  int t = blockIdx.x * 256 + threadIdx.x;
  if (t >= n4) return;
  float4 v = ((const float4*)in)[t];
  ushort4 o;
  o.x = f2b(v.x); o.y = f2b(v.y); o.z = f2b(v.z); o.w = f2b(v.w);
  ((ushort4*)out)[t] = o;
}

// ---------------- weight prep: permute rows to head-major, cast bf16 ----------------
// mat0: wq[h*64+d][c]       = Wq[d*12+h][c] * 0.125
// mat1: wkv[h*64+d][c]      = Wk[d*12+h][c]
// mat2: wkv[768+h*64+d][c]  = Wv[d*12+h][c]
// mat3: wo[j][h*64+d]       = Wo[j][d*12+h]
__global__ __launch_bounds__(256) void prep_weights(
    const float* __restrict__ Wq, const float* __restrict__ Wk,
    const float* __restrict__ Wv, const float* __restrict__ Wo,
    unsigned short* __restrict__ wq, unsigned short* __restrict__ wkv,
    unsigned short* __restrict__ wo) {
  int mat = blockIdx.y;
  int o = blockIdx.x * 256 + threadIdx.x;  // < 768*768
  int jrow = o / HID, c = o - jrow * HID;
  if (mat < 3) {
    int h = jrow >> 6, d = jrow & 63;
    const float* W = (mat == 0) ? Wq : ((mat == 1) ? Wk : Wv);
    float val = W[(d * NH + h) * HID + c];
    if (mat == 0) {
      wq[o] = f2b(val * 0.125f);
    } else if (mat == 1) {
      wkv[o] = f2b(val);
    } else {
      wkv[(size_t)HID * HID + o] = f2b(val);
    }
  } else {
    int h = c >> 6, d = c & 63;
    wo[o] = f2b(Wo[(size_t)jrow * HID + d * NH + h]);
  }
}

__global__ void prep_bias(const float* __restrict__ bq, const float* __restrict__ bk,
                          const float* __restrict__ bv, float* __restrict__ bqp,
                          float* __restrict__ bkvp) {
  int j = threadIdx.x;
  if (j >= HID) return;
  int h = j >> 6, d = j & 63, s = d * NH + h;
  bqp[j] = bq[s] * 0.125f;
  bkvp[j] = bk[s];
  bkvp[HID + j] = bv[s];
}

// ---------------- bf16 MFMA GEMM, 128x128 tile, BK=32, double-buffered prefetch ----------------
template <int OUT_F32>
__global__ __launch_bounds__(256) void gemm_nt(
    const unsigned short* __restrict__ A, const unsigned short* __restrict__ B,
    const float* __restrict__ bias, void* __restrict__ Cv, int M, int Nn, int K) {
  __shared__ __align__(16) unsigned short As[2][128 * 32];
  __shared__ __align__(16) unsigned short Bs[2][128 * 32];
  const int tid = threadIdx.x;
  const int lane = tid & 63;
  const int wid = tid >> 6;
  const int wr = wid >> 1, wc = wid & 1;
  const int l16 = lane & 15, kq = lane >> 4;
  const int m0 = blockIdx.x * 128;
  const int n0 = blockIdx.y * 128;

  f32x4 acc[4][4];
#pragma unroll
  for (int i = 0; i < 4; ++i)
#pragma unroll
    for (int j = 0; j < 4; ++j) acc[i][j] = (f32x4){0.f, 0.f, 0.f, 0.f};

  const int srow = tid >> 2;
  const int skg = tid & 3;
  const int scol = (skg ^ ((srow >> 1) & 3)) * 8;  // pre-swizzled source col
  const int sbase = (tid & ~63) * 8;               // wave-uniform LDS elem base

  const unsigned short* Ag = A + (size_t)(m0 + srow) * K + scol;
  const unsigned short* Bg = B + (size_t)(n0 + srow) * K + scol;
  const int kqA0 = (kq ^ ((l16 >> 1) & 3)) * 8;    // swizzled k-group for reads

#define STAGE(buf, kk)                                                                              \
  do {                                                                                              \
    __builtin_amdgcn_global_load_lds((const __attribute__((address_space(1))) void*)(Ag + (kk)),    \
                                     (__attribute__((address_space(3))) void*)(&As[buf][0] + sbase), 16, 0, 0); \
    __builtin_amdgcn_global_load_lds((const __attribute__((address_space(1))) void*)(Ag + (size_t)64 * K + (kk)), \
                                     (__attribute__((address_space(3))) void*)(&As[buf][0] + 2048 + sbase), 16, 0, 0); \
    __builtin_amdgcn_global_load_lds((const __attribute__((address_space(1))) void*)(Bg + (kk)),    \
                                     (__attribute__((address_space(3))) void*)(&Bs[buf][0] + sbase), 16, 0, 0); \
    __builtin_amdgcn_global_load_lds((const __attribute__((address_space(1))) void*)(Bg + (size_t)64 * K + (kk)), \
                                     (__attribute__((address_space(3))) void*)(&Bs[buf][0] + 2048 + sbase), 16, 0, 0); \
  } while (0)

  STAGE(0, 0);
  __syncthreads();
  int cur = 0;
  for (int k0 = 0; k0 < K; k0 += 32) {
    if (k0 + 32 < K) STAGE(cur ^ 1, k0 + 32);  // prefetch overlaps compute
    bf16x8 af[4], bfr[4];
#pragma unroll
    for (int i = 0; i < 4; ++i) {
      int ra = wr * 64 + i * 16 + l16;
      af[i] = *(const bf16x8*)(&As[cur][0] + ra * 32 + kqA0);
      int rb = wc * 64 + i * 16 + l16;
      bfr[i] = *(const bf16x8*)(&Bs[cur][0] + rb * 32 + kqA0);
    }
#pragma unroll
    for (int mi = 0; mi < 4; ++mi)
#pragma unroll
      for (int ni = 0; ni < 4; ++ni)
        acc[mi][ni] = __builtin_amdgcn_mfma_f32_16x16x32_bf16(af[mi], bfr[ni], acc[mi][ni], 0, 0, 0);
    __syncthreads();
    cur ^= 1;
  }
#undef STAGE

  float* Cf = (float*)Cv;
  unsigned short* Cb = (unsigned short*)Cv;
#pragma unroll
  for (int mi = 0; mi < 4; ++mi) {
    int grow = m0 + wr * 64 + mi * 16 + kq * 4;
#pragma unroll
    for (int ni = 0; ni < 4; ++ni) {
      int gcol = n0 + wc * 64 + ni * 16 + l16;
      float bv_ = bias[gcol];
#pragma unroll
      for (int r = 0; r < 4; ++r) {
        float v = acc[mi][ni][r] + bv_;
        if (OUT_F32)
          Cf[(size_t)(grow + r) * Nn + gcol] = v;
        else
          Cb[(size_t)(grow + r) * Nn + gcol] = f2b(v);
      }
    }
  }
}

// ---------------- rowptr from sorted row_idx ----------------
__global__ __launch_bounds__(256) void build_rowptr(const int* __restrict__ row_idx,
                                                    int* __restrict__ rowptr, int n, int E_) {
  int t = blockIdx.x * 256 + threadIdx.x;
  if (t > n) return;
  int lo = 0, hi = E_;
  while (lo < hi) {
    int mid = (lo + hi) >> 1;
    if (row_idx[mid] < t) lo = mid + 1; else hi = mid;
  }
  rowptr[t] = lo;
}

// ---------------- fused SDDMM + online segment-softmax + SpMM ----------------
// One wave per target row. q row in regs; per edge gather kv[col] (k: chunks 0..191,
// v: chunks 192..383 of ushort4). Head of chunk c = c>>4; lane l at set pp holds
// chunk pp*64+l -> head pp*4+(l>>4); 16-lane shfl_xor butterfly reduces the dot.
// Online softmax with defer-threshold 8 (rescale rare). attn_out written in-place
// over the q buffer (each wave fully consumes its q row first).
__global__ __launch_bounds__(256) void fused_edge(const int* __restrict__ rowptr,
                                                  const int* __restrict__ col_idx,
                                                  unsigned short* qo,  // q in, attn_out out
                                                  const unsigned short* __restrict__ kv,
                                                  int n) {
  int lane = threadIdx.x & 63;
  int row = blockIdx.x * 4 + (threadIdx.x >> 6);
  if (row >= n) return;
  int s0 = rowptr[row], s1 = rowptr[row + 1];

  const ushort4* qp = (const ushort4*)(qo + (size_t)row * HID);
  float qf[3][4];
#pragma unroll
  for (int pp = 0; pp < 3; ++pp) {
    ushort4 qv = qp[pp * 64 + lane];
    qf[pp][0] = b2f(qv.x); qf[pp][1] = b2f(qv.y);
    qf[pp][2] = b2f(qv.z); qf[pp][3] = b2f(qv.w);
  }

  float m0[3] = {-1e30f, -1e30f, -1e30f};
  float sum[3] = {0.f, 0.f, 0.f};
  float4 acc[3] = {};

  int c = (s0 < s1) ? col_idx[s0] : 0;
  for (int e = s0; e < s1; ++e) {
    int cnext = (e + 1 < s1) ? col_idx[e + 1] : c;  // software-pipeline the col load
    const ushort4* kp = (const ushort4*)(kv + (size_t)c * (2 * HID));
    ushort4 kc[3], vc[3];
#pragma unroll
    for (int pp = 0; pp < 3; ++pp) {
      kc[pp] = kp[pp * 64 + lane];
      vc[pp] = kp[192 + pp * 64 + lane];
    }
    float s[3];
#pragma unroll
    for (int pp = 0; pp < 3; ++pp) {
      float d = qf[pp][0] * b2f(kc[pp].x) + qf[pp][1] * b2f(kc[pp].y) +
                qf[pp][2] * b2f(kc[pp].z) + qf[pp][3] * b2f(kc[pp].w);
      d += __shfl_xor(d, 1);
      d += __shfl_xor(d, 2);
      d += __shfl_xor(d, 4);
      d += __shfl_xor(d, 8);
      s[pp] = d;
    }
#pragma unroll
    for (int pp = 0; pp < 3; ++pp) {
      float d = s[pp] - m0[pp];
      float p;
      if (d > 8.f) {  // rare rescale (defer-threshold); also handles first edge
        float r = __expf(-d);
        m0[pp] = s[pp];
        sum[pp] *= r;
        acc[pp].x *= r; acc[pp].y *= r; acc[pp].z *= r; acc[pp].w *= r;
        p = 1.f;
      } else {
        p = __expf(d);
      }
      sum[pp] += p;
      acc[pp].x += p * b2f(vc[pp].x);
      acc[pp].y += p * b2f(vc[pp].y);
      acc[pp].z += p * b2f(vc[pp].z);
      acc[pp].w += p * b2f(vc[pp].w);
    }
    c = cnext;
  }

  ushort4* op = (ushort4*)(qo + (size_t)row * HID);
#pragma unroll
  for (int pp = 0; pp < 3; ++pp) {
    float inv = (sum[pp] > 0.f) ? 1.f / sum[pp] : 0.f;
    ushort4 o;
    o.x = f2b(acc[pp].x * inv); o.y = f2b(acc[pp].y * inv);
    o.z = f2b(acc[pp].z * inv); o.w = f2b(acc[pp].w * inv);
    op[pp * 64 + lane] = o;
  }
}

// ---------------- launch ----------------
extern "C" void kernel_launch(void* const* d_in, const int* in_sizes, int n_in,
                              void* d_out, int out_size, void* d_ws, size_t ws_size,
                              hipStream_t stream) {
  const float* h_source = (const float*)d_in[0];
  const float* h_target = (const float*)d_in[1];
  const int* row_idx = (const int*)d_in[2];
  const int* col_idx = (const int*)d_in[3];
  const float* Wq = (const float*)d_in[4];
  const float* bq = (const float*)d_in[5];
  const float* Wk = (const float*)d_in[6];
  const float* bk = (const float*)d_in[7];
  const float* Wv = (const float*)d_in[8];
  const float* bv = (const float*)d_in[9];
  const float* Wo = (const float*)d_in[10];
  const float* bo = (const float*)d_in[11];
  float* out = (float*)d_out;

  const int n = in_sizes[0] / HID;   // 32768
  const int E_ = in_sizes[2];        // 1048576

  char* ws = (char*)d_ws;
  size_t off = 0;
  auto alloc = [&](size_t bytes) -> void* {
    off = (off + 255) & ~(size_t)255;
    void* p = ws + off;
    off += bytes;
    return p;
  };
  unsigned short* htb = (unsigned short*)alloc((size_t)n * HID * 2);   // h_target bf16
  unsigned short* hsb = (unsigned short*)alloc((size_t)n * HID * 2);   // h_source bf16
  unsigned short* qb = (unsigned short*)alloc((size_t)n * HID * 2);    // q; attn_out in-place
  unsigned short* kvb = (unsigned short*)alloc((size_t)n * 2 * HID * 2);  // kv interleaved
  unsigned short* wqp = (unsigned short*)alloc((size_t)HID * HID * 2);
  unsigned short* wkvp = (unsigned short*)alloc((size_t)2 * HID * HID * 2);
  unsigned short* wop = (unsigned short*)alloc((size_t)HID * HID * 2);
  float* bqp = (float*)alloc(HID * 4);
  float* bkvp = (float*)alloc(2 * HID * 4);
  int* rowptr = (int*)alloc((size_t)(n + 1) * 4);

  int n4 = n * HID / 4;
  cast_bf16<<<(n4 + 255) / 256, 256, 0, stream>>>(h_target, htb, n4);
  cast_bf16<<<(n4 + 255) / 256, 256, 0, stream>>>(h_source, hsb, n4);
  prep_weights<<<dim3(HID * HID / 256, 4), 256, 0, stream>>>(Wq, Wk, Wv, Wo, wqp, wkvp, wop);
  prep_bias<<<1, HID, 0, stream>>>(bq, bk, bv, bqp, bkvp);
  build_rowptr<<<(n + 1 + 255) / 256, 256, 0, stream>>>(row_idx, rowptr, n, E_);

  dim3 gq(n / 128, HID / 128);
  dim3 gkv(n / 128, 2 * HID / 128);
  gemm_nt<0><<<gq, 256, 0, stream>>>(htb, wqp, bqp, qb, n, HID, HID);
  gemm_nt<0><<<gkv, 256, 0, stream>>>(hsb, wkvp, bkvp, kvb, n, 2 * HID, HID);

  fused_edge<<<(n + 3) / 4, 256, 0, stream>>>(rowptr, col_idx, qb, kvb, n);

  gemm_nt<1><<<gq, 256, 0, stream>>>(qb, wop, bo, out, n, HID, HID);
}